// Round 9
// baseline (37.496 us; speedup 1.0000x reference)
//
#include <hip/hip_runtime.h>
#include <hip/hip_bf16.h>
#include <math.h>

#define T_   4096
#define E_   256
#define H_   4
#define HD_  64

typedef __attribute__((ext_vector_type(8))) short short8;
typedef __attribute__((ext_vector_type(4))) float f32x4;
typedef unsigned int u32;
typedef unsigned short ushort_t;

#define VT_PITCH 272   // must contain XOR range: max ((krow*2)|0x70)+16B = 256

typedef const __attribute__((address_space(1))) u32* gas_ptr;
typedef __attribute__((address_space(3))) u32* las_ptr;

__device__ __forceinline__ void gld_lds16(const void* g, void* l) {
    __builtin_amdgcn_global_load_lds((gas_ptr)g, (las_ptr)l, 16, 0, 0);
}

__device__ __forceinline__ ushort_t f2bf(float f) {
    __hip_bfloat16 h = __float2bfloat16(f);
    return *reinterpret_cast<ushort_t*>(&h);
}

// -------------------- Kernel 0: fp32 -> bf16 convert (x, Wqkv, Wout) ----------
__global__ __launch_bounds__(256) void cvt_kernel(
    const float* __restrict__ x, const float* __restrict__ wq,
    const float* __restrict__ wo,
    ushort_t* __restrict__ xb, ushort_t* __restrict__ wqb, ushort_t* __restrict__ wob)
{
    int idx = blockIdx.x * 256 + threadIdx.x;   // unit of 8 elems
    const float* src; ushort_t* dst; int off;
    if (idx < 262144)       { src = x;  dst = xb;  off = idx * 8; }
    else if (idx < 286720)  { src = wq; dst = wqb; off = (idx - 262144) * 8; }
    else                    { src = wo; dst = wob; off = (idx - 286720) * 8; }
    float4 a = *(const float4*)(src + off);
    float4 b = *(const float4*)(src + off + 4);
    short8 p;
    p[0] = (short)f2bf(a.x); p[1] = (short)f2bf(a.y);
    p[2] = (short)f2bf(a.z); p[3] = (short)f2bf(a.w);
    p[4] = (short)f2bf(b.x); p[5] = (short)f2bf(b.y);
    p[6] = (short)f2bf(b.z); p[7] = (short)f2bf(b.w);
    *(short8*)(dst + off) = p;
}

// -------------------- Kernel 1: qkv MFMA GEMM (r3 structure, unchanged) ------
__global__ __launch_bounds__(256) void qkv_kernel(
    const char* __restrict__ A, const char* __restrict__ Bw,
    const float* __restrict__ bias,
    ushort_t* __restrict__ o0, ushort_t* __restrict__ o1, ushort_t* __restrict__ o2)
{
    __shared__ __align__(16) char As[2][16384];   // [128][64] bf16, swz
    __shared__ __align__(16) char Bs[2][8192];    // [64][64]  bf16, swz
    const int tid  = threadIdx.x;
    const int lane = tid & 63;
    const int wid  = tid >> 6;
    const int m0   = blockIdx.y * 128;
    const int bx   = blockIdx.x;
    const int n0   = bx * 64;
    const int ln   = lane & 15;
    const int lg   = lane >> 4;

    f32x4 acc[2][4];
    #pragma unroll
    for (int i = 0; i < 2; ++i)
        #pragma unroll
        for (int j = 0; j < 4; ++j)
            acc[i][j] = (f32x4){0.f, 0.f, 0.f, 0.f};

    auto stage = [&](int buf, int ks) {
        const int kb = ks * 128;
        #pragma unroll
        for (int i = 0; i < 4; ++i) {
            int u   = wid * 4 + i;
            int o   = u * 1024 + lane * 16;
            int row = o >> 7;
            int cb  = o & 127;
            int sc  = cb ^ ((row & 7) << 4);
            gld_lds16(A + (size_t)(m0 + row) * 512 + kb + sc, &As[buf][u * 1024]);
        }
        #pragma unroll
        for (int i = 0; i < 2; ++i) {
            int u   = wid * 2 + i;
            int o   = u * 1024 + lane * 16;
            int row = o >> 7;
            int cb  = o & 127;
            int sc  = cb ^ ((row & 7) << 4);
            gld_lds16(Bw + (size_t)(n0 + row) * 512 + kb + sc, &Bs[buf][u * 1024]);
        }
    };

    auto compute = [&](int buf) {
        #pragma unroll
        for (int k2 = 0; k2 < 2; ++k2) {
            short8 af[2], bfr[4];
            #pragma unroll
            for (int mf = 0; mf < 2; ++mf) {
                int row = wid * 32 + mf * 16 + ln;
                int off = (k2 * 64 + lg * 16) ^ ((row & 7) << 4);
                af[mf] = *(const short8*)(&As[buf][row * 128 + off]);
            }
            #pragma unroll
            for (int nf = 0; nf < 4; ++nf) {
                int row = nf * 16 + ln;
                int off = (k2 * 64 + lg * 16) ^ ((row & 7) << 4);
                bfr[nf] = *(const short8*)(&Bs[buf][row * 128 + off]);
            }
            #pragma unroll
            for (int mf = 0; mf < 2; ++mf)
                #pragma unroll
                for (int nf = 0; nf < 4; ++nf)
                    acc[mf][nf] = __builtin_amdgcn_mfma_f32_16x16x32_bf16(
                        af[mf], bfr[nf], acc[mf][nf], 0, 0, 0);
        }
    };

    stage(0, 0);
    __syncthreads();
    #pragma unroll
    for (int t = 0; t < 4; ++t) {
        if (t < 3) stage((t + 1) & 1, t + 1);
        compute(t & 1);
        __syncthreads();
    }

    const int which = bx >> 2;              // 0=q 1=k 2=v (uniform per block)
    const int h     = bx & 3;
    ushort_t* dst = (which == 0) ? o0 : (which == 1) ? o1 : o2;
    const float scale = (which == 0) ? 0.125f : 1.0f;
    #pragma unroll
    for (int nf = 0; nf < 4; ++nf) {
        int d = nf * 16 + ln;
        float bv = bias[n0 + d];
        #pragma unroll
        for (int mf = 0; mf < 2; ++mf)
            #pragma unroll
            for (int r = 0; r < 4; ++r) {
                int m  = m0 + wid * 32 + mf * 16 + lg * 4 + r;
                int bb = m >> 12;
                int t  = m & (T_ - 1);
                float v = (acc[mf][nf][r] + bv) * scale;
                dst[((size_t)(bb * H_ + h) * T_ + t) * HD_ + d] = f2bf(v);
            }
    }
}

// -------------------- Kernel 2: fused attention + output projection ----------
// Block = 32 t-rows x all 4 heads of one batch. Grid (128, 2), 4 waves,
// wave = head. K row-major XOR-swz. V transposed at staging to per-head
// Vt[d][k] (VT_PITCH=272 B: contains the k-XOR swizzle range, unlike r8's
// 208 which overflowed rows). P overlays the wave's own K slice; O (32x256
// bf16, row-XOR swz) overlays Vt after the PV barrier; proj done in-block.
__global__ __launch_bounds__(256) void attnproj_kernel(
    const ushort_t* __restrict__ q, const ushort_t* __restrict__ k,
    const ushort_t* __restrict__ v, const ushort_t* __restrict__ wob,
    const float* __restrict__ bout, float* __restrict__ out)
{
    __shared__ __align__(16) char smem[49152 + 4 * 64 * VT_PITCH];
    char* Ks = smem;          // [4][96][128B] swz; wave's P overlays own slice
    char* Vt = smem + 49152;  // [4*64 d][VT_PITCH]: elem (h,d,krow) at
                              // (h*64+d)*VT_PITCH + ((krow*2) ^ (((d>>3)&7)<<4))
                              // O[32][512B swz] overlays Vt[0,16384) post-PV

    const int tid = threadIdx.x;
    const int b   = blockIdx.y;
    const int t0  = blockIdx.x * 32;
    const int kbase = t0 - 32;
    const int wv_ = tid >> 6;               // wave = head
    const int ln  = tid & 15;
    const int lg  = (tid & 63) >> 4;

    // ---- stage: 4 heads x 96 kv rows, K + V (zeros OOB) ----
    int4 kreg[12], vreg[12];
    #pragma unroll
    for (int l = 0; l < 12; ++l) {
        int u = tid + l * 256;              // 0..3071 = 4h x 96row x 8unit
        int ru = u >> 3;
        int h = ru / 96;
        int krow = ru - h * 96;
        int c = u & 7;
        int g = kbase + krow;
        bool ok = (unsigned)g < (unsigned)T_;
        size_t base = ((size_t)(b * 4 + h) * T_ + (ok ? g : 0)) * 128 + c * 16;
        kreg[l] = ok ? *(const int4*)((const char*)k + base) : make_int4(0, 0, 0, 0);
        vreg[l] = ok ? *(const int4*)((const char*)v + base) : make_int4(0, 0, 0, 0);
    }
    // Q fragments (issued early, hide under LDS writes)
    short8 qf[2][2];
    #pragma unroll
    for (int mf = 0; mf < 2; ++mf)
        #pragma unroll
        for (int k2 = 0; k2 < 2; ++k2)
            qf[mf][k2] = *(const short8*)((const char*)q +
                ((size_t)(b * 4 + wv_) * T_ + t0 + mf * 16 + ln) * 128
                + k2 * 64 + lg * 16);

    #pragma unroll
    for (int l = 0; l < 12; ++l) {
        int u = tid + l * 256;
        int ru = u >> 3;
        int h = ru / 96;
        int krow = ru - h * 96;
        int c = u & 7;
        *(int4*)(Ks + (h * 96 + krow) * 128 + ((c * 16) ^ ((krow & 7) << 4))) = kreg[l];
        const u32* wvp = (const u32*)&vreg[l];
        #pragma unroll
        for (int j = 0; j < 8; ++j) {
            int d = c * 8 + j;
            ushort_t hv = (j & 1) ? (ushort_t)(wvp[j >> 1] >> 16)
                                  : (ushort_t)(wvp[j >> 1] & 0xffffu);
            *(ushort_t*)(Vt + (size_t)(h * 64 + d) * VT_PITCH +
                         ((krow * 2) ^ (((d >> 3) & 7) << 4))) = hv;
        }
    }
    __syncthreads();

    // ---- S = Q K^T (32x96 band tile per head; 24 MFMA) ----
    f32x4 sa[2][6];
    #pragma unroll
    for (int mf = 0; mf < 2; ++mf)
        #pragma unroll
        for (int nf = 0; nf < 6; ++nf) sa[mf][nf] = (f32x4){0.f, 0.f, 0.f, 0.f};
    #pragma unroll
    for (int k2 = 0; k2 < 2; ++k2)
        #pragma unroll
        for (int nf = 0; nf < 6; ++nf) {
            int krow = nf * 16 + ln;
            short8 kf = *(const short8*)(Ks + (wv_ * 96 + krow) * 128 +
                            ((k2 * 64 + lg * 16) ^ ((krow & 7) << 4)));
            sa[0][nf] = __builtin_amdgcn_mfma_f32_16x16x32_bf16(qf[0][k2], kf, sa[0][nf], 0, 0, 0);
            sa[1][nf] = __builtin_amdgcn_mfma_f32_16x16x32_bf16(qf[1][k2], kf, sa[1][nf], 0, 0, 0);
        }

    // ---- band mask + softmax (C-layout m = mf*16+4lg+r, n = nf*16+ln) ----
    float inv_[2][4];
    #pragma unroll
    for (int mf = 0; mf < 2; ++mf)
        #pragma unroll
        for (int r = 0; r < 4; ++r) {
            int m = mf * 16 + 4 * lg + r;
            #pragma unroll
            for (int nf = 0; nf < 6; ++nf) {
                int diff = nf * 16 + ln - m;        // in-window iff 0..64
                if (diff < 0 || diff > 64) sa[mf][nf][r] = -1e30f;
            }
            float mx = sa[mf][0][r];
            #pragma unroll
            for (int nf = 1; nf < 6; ++nf) mx = fmaxf(mx, sa[mf][nf][r]);
            mx = fmaxf(mx, __shfl_xor(mx, 1));
            mx = fmaxf(mx, __shfl_xor(mx, 2));
            mx = fmaxf(mx, __shfl_xor(mx, 4));
            mx = fmaxf(mx, __shfl_xor(mx, 8));
            float su = 0.f;
            #pragma unroll
            for (int nf = 0; nf < 6; ++nf) {
                float e = __expf(sa[mf][nf][r] - mx);
                sa[mf][nf][r] = e;
                su += e;
            }
            su += __shfl_xor(su, 1);
            su += __shfl_xor(su, 2);
            su += __shfl_xor(su, 4);
            su += __shfl_xor(su, 8);
            inv_[mf][r] = 1.f / su;
        }

    // ---- P -> LDS (overlay own head's K slice; wave-private, no barrier) ----
    char* Pw = Ks + wv_ * 12288;                // 32 rows x 208B pitch
    #pragma unroll
    for (int mf = 0; mf < 2; ++mf)
        #pragma unroll
        for (int nf = 0; nf < 6; ++nf)
            #pragma unroll
            for (int r = 0; r < 4; ++r)
                *(ushort_t*)(Pw + (mf * 16 + 4 * lg + r) * 208 + (nf * 16 + ln) * 2)
                    = f2bf(sa[mf][nf][r]);

    // ---- O = P x V (24 MFMA, Vt short8 B-frags) ----
    f32x4 oa[2][4];
    #pragma unroll
    for (int mf = 0; mf < 2; ++mf)
        #pragma unroll
        for (int nf = 0; nf < 4; ++nf) oa[mf][nf] = (f32x4){0.f, 0.f, 0.f, 0.f};
    #pragma unroll
    for (int ks = 0; ks < 3; ++ks) {
        short8 pa0 = *(const short8*)(Pw + ln * 208 + ks * 64 + lg * 16);
        short8 pa1 = *(const short8*)(Pw + (16 + ln) * 208 + ks * 64 + lg * 16);
        #pragma unroll
        for (int nf = 0; nf < 4; ++nf) {
            int d = nf * 16 + ln;
            short8 vb = *(const short8*)(Vt + (size_t)(wv_ * 64 + d) * VT_PITCH +
                           ((ks * 64 + lg * 16) ^ (((d >> 3) & 7) << 4)));
            oa[0][nf] = __builtin_amdgcn_mfma_f32_16x16x32_bf16(pa0, vb, oa[0][nf], 0, 0, 0);
            oa[1][nf] = __builtin_amdgcn_mfma_f32_16x16x32_bf16(pa1, vb, oa[1][nf], 0, 0, 0);
        }
    }

    // ---- O (bf16, scaled) -> LDS overlay on Vt; then proj ----
    __syncthreads();                            // all waves done with Vt reads
    char* OL = Vt;                              // [32][512B], row-XOR swz
    #pragma unroll
    for (int mf = 0; mf < 2; ++mf)
        #pragma unroll
        for (int nf = 0; nf < 4; ++nf)
            #pragma unroll
            for (int r = 0; r < 4; ++r) {
                int row = mf * 16 + 4 * lg + r;
                int col = wv_ * 64 + nf * 16 + ln;
                *(ushort_t*)(OL + row * 512 + ((col * 2) ^ ((row & 7) << 4)))
                    = f2bf(oa[mf][nf][r] * inv_[mf][r]);
            }
    __syncthreads();

    f32x4 pacc[2][4];
    #pragma unroll
    for (int mf = 0; mf < 2; ++mf)
        #pragma unroll
        for (int nf = 0; nf < 4; ++nf) pacc[mf][nf] = (f32x4){0.f, 0.f, 0.f, 0.f};
    #pragma unroll
    for (int ks = 0; ks < 8; ++ks) {
        short8 paf[2];
        #pragma unroll
        for (int mf = 0; mf < 2; ++mf) {
            int row = mf * 16 + ln;
            paf[mf] = *(const short8*)(OL + row * 512 +
                          ((ks * 64 + lg * 16) ^ ((row & 7) << 4)));
        }
        #pragma unroll
        for (int nf = 0; nf < 4; ++nf) {
            short8 bf = *(const short8*)(wob + ((size_t)(wv_ * 64 + nf * 16 + ln)) * 256
                                         + ks * 32 + lg * 8);
            pacc[0][nf] = __builtin_amdgcn_mfma_f32_16x16x32_bf16(paf[0], bf, pacc[0][nf], 0, 0, 0);
            pacc[1][nf] = __builtin_amdgcn_mfma_f32_16x16x32_bf16(paf[1], bf, pacc[1][nf], 0, 0, 0);
        }
    }

    #pragma unroll
    for (int nf = 0; nf < 4; ++nf) {
        int eo = wv_ * 64 + nf * 16 + ln;
        float bv = bout[eo];
        #pragma unroll
        for (int mf = 0; mf < 2; ++mf)
            #pragma unroll
            for (int r = 0; r < 4; ++r) {
                int t = t0 + mf * 16 + 4 * lg + r;
                out[((size_t)b * T_ + t) * E_ + eo] = pacc[mf][nf][r] + bv;
            }
    }
}

extern "C" void kernel_launch(void* const* d_in, const int* in_sizes, int n_in,
                              void* d_out, int out_size, void* d_ws, size_t ws_size,
                              hipStream_t stream) {
    const float* x    = (const float*)d_in[0];
    const float* Wqkv = (const float*)d_in[1];
    const float* bqkv = (const float*)d_in[2];
    const float* Wout = (const float*)d_in[3];
    const float* bout = (const float*)d_in[4];
    float* out = (float*)d_out;

    char* ws = (char*)d_ws;
    ushort_t* xb  = (ushort_t*)(ws);                 // 4 MB  (8192x256)
    ushort_t* wqb = (ushort_t*)(ws + 4194304);       // 384 KB (768x256)
    ushort_t* wob = (ushort_t*)(ws + 4587520);       // 128 KB (256x256)
    ushort_t* qb  = (ushort_t*)(ws + 4718592);       // 4 MB  [BH][T][64]
    ushort_t* kbp = (ushort_t*)(ws + 8912896);       // 4 MB
    ushort_t* vbp = (ushort_t*)(ws + 13107200);      // 4 MB

    cvt_kernel<<<1152, 256, 0, stream>>>(x, Wqkv, Wout, xb, wqb, wob);
    qkv_kernel<<<dim3(12, 64), 256, 0, stream>>>(
        (const char*)xb, (const char*)wqb, bqkv, qb, kbp, vbp);
    attnproj_kernel<<<dim3(128, 2), 256, 0, stream>>>(qb, kbp, vbp, wob, bout, out);
}